// Round 1
// baseline (162.137 us; speedup 1.0000x reference)
//
#include <hip/hip_runtime.h>

#define S 48
#define D 4
#define PADC 2
#define P 52
#define SITES (S * S * S)        // 110592
#define PADVOL (P * P * P)       // 140608
#define N_IN 2048
#define H1 1024
#define H2 128
#define OUTN 10
#define ROWS_PER 256
#define NCH (SITES / ROWS_PER)   // 432

__global__ void scatter_k(const float* __restrict__ vin,
                          const int* __restrict__ idx,
                          float* __restrict__ nm) {
    int t = blockIdx.x * blockDim.x + threadIdx.x;
    if (t < N_IN) {
        int x = idx[t * 3 + 0] + PADC;
        int y = idx[t * 3 + 1] + PADC;
        int z = idx[t * 3 + 2] + PADC;
        atomicAdd(&nm[(x * P + y) * P + z], vin[t]);
    }
}

__global__ __launch_bounds__(256) void step_k(const float* __restrict__ src,
                                              const float* __restrict__ syn,
                                              float* __restrict__ dst) {
    int s = blockIdx.x * 256 + threadIdx.x;   // grid sized exactly SITES/256
    int z = s % S;
    int q = s / S;
    int y = q % S;
    int x = q / S;
    const float4* sv = (const float4*)(syn + (size_t)s * 64);
    float acc = 0.0f;
#pragma unroll
    for (int a = 0; a < D; a++) {
#pragma unroll
        for (int b = 0; b < D; b++) {
            const float* row = src + ((x + a) * P + (y + b)) * P + z;
            float4 w = sv[a * D + b];
            acc += w.x * row[0] + w.y * row[1] + w.z * row[2] + w.w * row[3];
        }
    }
    acc = fmaxf(acc, 0.0f) * 0.9f;
    dst[((x + PADC) * P + (y + PADC)) * P + (z + PADC)] = acc;
}

// Layer 1 GEMV: x[110592] @ W1[110592,1024] -> partial sums per row-chunk.
// Each block: 256 rows x 1024 cols; thread t owns 4 consecutive cols (float4).
// Wave-uniform skip of rows where x[i] == 0 (exact: skipped terms are zero).
__global__ __launch_bounds__(256) void gemv1_k(const float* __restrict__ nmfin,
                                               const float* __restrict__ W1,
                                               float* __restrict__ partial) {
    __shared__ float xs[ROWS_PER];
    int blk = blockIdx.x;
    int t = threadIdx.x;
    int i0 = blk * ROWS_PER;
    {
        int i = i0 + t;
        int z = i % S;
        int q = i / S;
        int y = q % S;
        int x = q / S;
        xs[t] = nmfin[((x + PADC) * P + (y + PADC)) * P + (z + PADC)];
    }
    __syncthreads();
    float4 acc = {0.f, 0.f, 0.f, 0.f};
    const float4* W4 = (const float4*)W1;
    for (int i = 0; i < ROWS_PER; i++) {
        float xv = xs[i];
        if (xv != 0.0f) {
            float4 w = W4[(size_t)(i0 + i) * (H1 / 4) + t];
            acc.x += xv * w.x;
            acc.y += xv * w.y;
            acc.z += xv * w.z;
            acc.w += xv * w.w;
        }
    }
    ((float4*)(partial + (size_t)blk * H1))[t] = acc;
}

__global__ __launch_bounds__(256) void reduce1_k(const float* __restrict__ partial,
                                                 const float* __restrict__ b1,
                                                 float* __restrict__ y1) {
    int j = blockIdx.x * 256 + threadIdx.x;   // 4 blocks x 256 = 1024
    float s = b1[j];
#pragma unroll 8
    for (int r = 0; r < NCH; r++) s += partial[(size_t)r * H1 + j];
    y1[j] = fmaxf(s, 0.0f);
}

__global__ __launch_bounds__(128) void gemv2_k(const float* __restrict__ y1,
                                               const float* __restrict__ W2,
                                               float* __restrict__ partial2) {
    __shared__ float ys[128];
    int b = blockIdx.x;   // 8 blocks, 128 rows each
    int t = threadIdx.x;
    ys[t] = y1[b * 128 + t];
    __syncthreads();
    float acc = 0.0f;
#pragma unroll 8
    for (int i = 0; i < 128; i++)
        acc += ys[i] * W2[(size_t)(b * 128 + i) * H2 + t];
    partial2[b * H2 + t] = acc;
}

__global__ __launch_bounds__(128) void final_k(const float* __restrict__ partial2,
                                               const float* __restrict__ b2,
                                               const float* __restrict__ W3,
                                               const float* __restrict__ b3,
                                               float* __restrict__ out) {
    __shared__ float y2[H2];
    int t = threadIdx.x;
    float s = b2[t];
#pragma unroll
    for (int k = 0; k < 8; k++) s += partial2[k * H2 + t];
    y2[t] = fmaxf(s, 0.0f);
    __syncthreads();
    if (t < OUTN) {
        float o = b3[t];
#pragma unroll 8
        for (int i = 0; i < H2; i++) o += y2[i] * W3[i * OUTN + t];
        out[t] = o;
    }
}

extern "C" void kernel_launch(void* const* d_in, const int* in_sizes, int n_in,
                              void* d_out, int out_size, void* d_ws, size_t ws_size,
                              hipStream_t stream) {
    const float* vinput  = (const float*)d_in[1];
    const float* synapse = (const float*)d_in[2];
    const float* W1      = (const float*)d_in[3];
    const float* b1      = (const float*)d_in[4];
    const float* W2      = (const float*)d_in[5];
    const float* b2      = (const float*)d_in[6];
    const float* W3      = (const float*)d_in[7];
    const float* b3      = (const float*)d_in[8];
    const int* node_idx  = (const int*)d_in[9];

    float* ws = (float*)d_ws;
    float* nm0 = ws;                       // 140608
    float* nm1 = nm0 + PADVOL;             // 140608
    float* partial1 = nm1 + PADVOL;        // NCH*1024 = 442368
    float* y1 = partial1 + (size_t)NCH * H1;  // 1024
    float* partial2 = y1 + H1;             // 1024
    float* out = (float*)d_out;

    // zero both nm buffers (pads must be zero; scatter accumulates)
    hipMemsetAsync(nm0, 0, 2 * (size_t)PADVOL * sizeof(float), stream);

    scatter_k<<<N_IN / 256, 256, 0, stream>>>(vinput, node_idx, nm0);

    const float* src = nm0;
    float* dst = nm1;
    for (int r = 0; r < 5; r++) {
        step_k<<<SITES / 256, 256, 0, stream>>>(src, synapse, dst);
        float* tmp = (float*)src;
        src = dst;
        dst = tmp;
    }
    // final interior now lives in `src`

    gemv1_k<<<NCH, 256, 0, stream>>>(src, W1, partial1);
    reduce1_k<<<H1 / 256, 256, 0, stream>>>(partial1, b1, y1);
    gemv2_k<<<8, 128, 0, stream>>>(y1, W2, partial2);
    final_k<<<1, 128, 0, stream>>>(partial2, b2, W3, b3, out);
}